// Round 1
// baseline (482.152 us; speedup 1.0000x reference)
//
#include <hip/hip_runtime.h>
#include <hip/hip_bf16.h>
#include <stdint.h>

typedef __bf16 bf16x8 __attribute__((ext_vector_type(8)));
typedef float f32x4 __attribute__((ext_vector_type(4)));

#define LOG2E 1.4426950408889634f

// ---------------- prep: build indices from batch_sizes ----------------
__global__ void prep_kernel(const int* __restrict__ bs, int T,
                            const int* __restrict__ sentences,
                            int* __restrict__ hdr, float* __restrict__ fhdr,
                            int* __restrict__ row_ctx, int* __restrict__ row_tok) {
    __shared__ int off[1025];
    if (threadIdx.x == 0) {
        int acc = 0; off[0] = 0;
        for (int t = 0; t < T; ++t) { acc += bs[t]; off[t + 1] = acc; }
    }
    __syncthreads();
    const int total = off[T];
    const int Nf = total - off[1];          // sum bs[1:]
    const int Nb = total - off[2];          // sum bs[2:]
    // forward: t = 1..T-1, ctx = off[t-1]+p, tgt = off[t]+p
    for (int t = 1; t < T; ++t) {
        int start = off[t] - off[1];
        int cnt = off[t + 1] - off[t];
        for (int p = threadIdx.x; p < cnt; p += blockDim.x) {
            row_ctx[start + p] = off[t - 1] + p;
            row_tok[start + p] = sentences[off[t] + p];
        }
    }
    // backward: i = 1..T-2, ctx = off[i+1]+p, tgt = off[i]+p
    for (int i = 1; i < T - 1; ++i) {
        int start = Nf + off[i + 1] - off[2];
        int cnt = off[i + 2] - off[i + 1];
        for (int p = threadIdx.x; p < cnt; p += blockDim.x) {
            row_ctx[start + p] = off[i + 1] + p;
            row_tok[start + p] = sentences[off[i] + p];
        }
    }
    if (threadIdx.x == 0) {
        hdr[0] = Nf + Nb;   // M_total
        hdr[1] = Nf;
        int bs0 = off[1];
        int bsl = off[T] - off[T - 1];
        fhdr[0] = (float)(2 * total - bs0 - bsl);  // denom
    }
}

// ---------------- W f32 -> bf16 ----------------
__global__ void wconv_kernel(const float* __restrict__ W,
                             __hip_bfloat16* __restrict__ Wb, long n4) {
    long i = (long)blockIdx.x * blockDim.x + threadIdx.x;
    if (i >= n4) return;
    float4 v = ((const float4*)W)[i];
    __hip_bfloat16 a0 = __float2bfloat16(v.x), a1 = __float2bfloat16(v.y);
    __hip_bfloat16 a2 = __float2bfloat16(v.z), a3 = __float2bfloat16(v.w);
    ushort4 pk;
    pk.x = *(unsigned short*)&a0; pk.y = *(unsigned short*)&a1;
    pk.z = *(unsigned short*)&a2; pk.w = *(unsigned short*)&a3;
    ((ushort4*)Wb)[i] = pk;
}

// ---------------- gather packed context rows -> bf16, zero S ----------------
__global__ void gather_kernel(const float* __restrict__ hs,
                              const int* __restrict__ row_ctx,
                              const int* __restrict__ hdr,
                              __hip_bfloat16* __restrict__ Hc,
                              float* __restrict__ S, int D2, int D) {
    const int m = blockIdx.x;
    const int M = hdr[0], Nf = hdr[1];
    const int Mpad = (M + 127) & ~127;
    if (m >= Mpad) return;
    if (threadIdx.x == 0) S[m] = 0.f;
    ushort4* dst = (ushort4*)(Hc + (size_t)m * D);
    if (m >= M) {
        ushort4 z; z.x = z.y = z.z = z.w = 0;
        for (int i = threadIdx.x; i < D / 4; i += blockDim.x) dst[i] = z;
        return;
    }
    const int ctx = row_ctx[m];
    const float4* src = (const float4*)(hs + (size_t)ctx * D2 + (m < Nf ? 0 : D));
    for (int i = threadIdx.x; i < D / 4; i += blockDim.x) {
        float4 v = src[i];
        __hip_bfloat16 a0 = __float2bfloat16(v.x), a1 = __float2bfloat16(v.y);
        __hip_bfloat16 a2 = __float2bfloat16(v.z), a3 = __float2bfloat16(v.w);
        ushort4 pk;
        pk.x = *(unsigned short*)&a0; pk.y = *(unsigned short*)&a1;
        pk.z = *(unsigned short*)&a2; pk.w = *(unsigned short*)&a3;
        dst[i] = pk;
    }
}

// ---------------- main GEMM + sum-exp epilogue ----------------
// C[m][v] = sum_k Hc[m][k] * W[v][k]; S[m] += sum_v exp(C[m][v] + bias[v])
template <bool CONVB>
__global__ __launch_bounds__(256, 2)
void gemm_lse_kernel(const __hip_bfloat16* __restrict__ A,
                     const void* __restrict__ Bvoid,
                     const float* __restrict__ fb,
                     const float* __restrict__ bb,
                     float* __restrict__ S,
                     const int* __restrict__ hdr, int K) {
    const int M = hdr[0], Nf = hdr[1];
    const int bm = blockIdx.y, bn = blockIdx.x;
    if (bm * 128 >= M) return;

    __shared__ __hip_bfloat16 lA[128 * 32];
    __shared__ __hip_bfloat16 lB[128 * 32];

    const int tid = threadIdx.x;
    const int wid = tid >> 6, lane = tid & 63;
    const int wm = wid >> 1, wn = wid & 1;

    f32x4 acc[4][4];
#pragma unroll
    for (int i = 0; i < 4; ++i)
#pragma unroll
        for (int j = 0; j < 4; ++j) acc[i][j] = (f32x4)0.f;

    const char* gA = (const char*)(A + (size_t)bm * 128 * K);
    const __hip_bfloat16* Bb = (const __hip_bfloat16*)Bvoid;
    const float* Bf = (const float*)Bvoid;
    const int Kb = K * 2;  // bf16 row stride in bytes

    for (int kt = 0; kt < K; kt += 32) {
        __syncthreads();  // previous tile fully consumed
#pragma unroll
        for (int j = 0; j < 2; ++j) {
            const int chunk = j * 256 + tid;      // 512 x 16B chunks per tile
            const int row = chunk >> 2;           // 64B per row of 32 bf16
            const int colb = (chunk & 3) * 16;
            __builtin_amdgcn_global_load_lds(
                (const __attribute__((address_space(1))) uint32_t*)(gA + (size_t)row * Kb + (size_t)kt * 2 + colb),
                (__attribute__((address_space(3))) uint32_t*)((char*)lA + j * 4096 + wid * 1024),
                16, 0, 0);
            if constexpr (!CONVB) {
                const char* gB = (const char*)(Bb + (size_t)bn * 128 * K);
                __builtin_amdgcn_global_load_lds(
                    (const __attribute__((address_space(1))) uint32_t*)(gB + (size_t)row * Kb + (size_t)kt * 2 + colb),
                    (__attribute__((address_space(3))) uint32_t*)((char*)lB + j * 4096 + wid * 1024),
                    16, 0, 0);
            } else {
                const int cole = (chunk & 3) * 8;
                const float4* src = (const float4*)(Bf + (size_t)(bn * 128 + row) * K + kt + cole);
                float4 v0 = src[0], v1 = src[1];
                union { __hip_bfloat16 h[8]; int4 i4; } u;
                u.h[0] = __float2bfloat16(v0.x); u.h[1] = __float2bfloat16(v0.y);
                u.h[2] = __float2bfloat16(v0.z); u.h[3] = __float2bfloat16(v0.w);
                u.h[4] = __float2bfloat16(v1.x); u.h[5] = __float2bfloat16(v1.y);
                u.h[6] = __float2bfloat16(v1.z); u.h[7] = __float2bfloat16(v1.w);
                *(int4*)((char*)lB + chunk * 16) = u.i4;
            }
        }
        __syncthreads();  // staging visible

        bf16x8 a[4], b[4];
#pragma unroll
        for (int mf = 0; mf < 4; ++mf) {
            int r = wm * 64 + mf * 16 + (lane & 15);
            a[mf] = *(const bf16x8*)(lA + r * 32 + (lane >> 4) * 8);
        }
#pragma unroll
        for (int nf = 0; nf < 4; ++nf) {
            int r = wn * 64 + nf * 16 + (lane & 15);
            b[nf] = *(const bf16x8*)(lB + r * 32 + (lane >> 4) * 8);
        }
#pragma unroll
        for (int mf = 0; mf < 4; ++mf)
#pragma unroll
            for (int nf = 0; nf < 4; ++nf)
                acc[mf][nf] = __builtin_amdgcn_mfma_f32_16x16x32_bf16(a[mf], b[nf], acc[mf][nf], 0, 0, 0);
    }

    // epilogue: bias + exp + row-sum + atomic
    float fbv[4], bbv[4];
#pragma unroll
    for (int nf = 0; nf < 4; ++nf) {
        int v = bn * 128 + wn * 64 + nf * 16 + (lane & 15);
        fbv[nf] = fb[v]; bbv[nf] = bb[v];
    }
#pragma unroll
    for (int mf = 0; mf < 4; ++mf) {
#pragma unroll
        for (int j = 0; j < 4; ++j) {
            int m = bm * 128 + wm * 64 + mf * 16 + (lane >> 4) * 4 + j;
            if (m >= M) continue;   // uniform within each 16-lane shuffle group
            const bool isf = m < Nf;
            float ps = 0.f;
#pragma unroll
            for (int nf = 0; nf < 4; ++nf) {
                float logit = acc[mf][nf][j] + (isf ? fbv[nf] : bbv[nf]);
                ps += exp2f(logit * LOG2E);
            }
#pragma unroll
            for (int s = 1; s < 16; s <<= 1) ps += __shfl_xor(ps, s);
            if ((lane & 15) == 0) atomicAdd(&S[m], ps);
        }
    }
}

// ---------------- gold logits (exact f32) ----------------
__global__ void gold_kernel(const float* __restrict__ hs,
                            const float* __restrict__ W,
                            const float* __restrict__ fb,
                            const float* __restrict__ bb,
                            const int* __restrict__ row_ctx,
                            const int* __restrict__ row_tok,
                            const int* __restrict__ hdr,
                            float* __restrict__ goldv, int D2, int D) {
    const int m = blockIdx.x;
    const int M = hdr[0];
    if (m >= M) return;
    const int Nf = hdr[1];
    const int ctx = row_ctx[m], tok = row_tok[m];
    const float4* h = (const float4*)(hs + (size_t)ctx * D2 + (m < Nf ? 0 : D));
    const float4* w = (const float4*)(W + (size_t)tok * D);
    float s = 0.f;
    for (int i = threadIdx.x; i < D / 4; i += blockDim.x) {
        float4 a = h[i], b = w[i];
        s += a.x * b.x + a.y * b.y + a.z * b.z + a.w * b.w;
    }
#pragma unroll
    for (int d = 1; d < 64; d <<= 1) s += __shfl_xor(s, d);
    __shared__ float wsum[4];
    const int wid = threadIdx.x >> 6, lane = threadIdx.x & 63;
    if (lane == 0) wsum[wid] = s;
    __syncthreads();
    if (threadIdx.x == 0) {
        float tot = wsum[0] + wsum[1] + wsum[2] + wsum[3];
        tot += (m < Nf ? fb[tok] : bb[tok]);
        goldv[m] = tot;
    }
}

// ---------------- final reduce ----------------
__global__ void final_kernel(const float* __restrict__ S,
                             const float* __restrict__ goldv,
                             const int* __restrict__ hdr,
                             const float* __restrict__ fhdr,
                             float* __restrict__ out) {
    const int M = hdr[0];
    float s = 0.f;
    for (int m = threadIdx.x; m < M; m += blockDim.x)
        s += logf(S[m]) - goldv[m];
#pragma unroll
    for (int d = 1; d < 64; d <<= 1) s += __shfl_xor(s, d);
    __shared__ float wsum[4];
    const int wid = threadIdx.x >> 6, lane = threadIdx.x & 63;
    if (lane == 0) wsum[wid] = s;
    __syncthreads();
    if (threadIdx.x == 0)
        out[0] = (wsum[0] + wsum[1] + wsum[2] + wsum[3]) / fhdr[0];
}

extern "C" void kernel_launch(void* const* d_in, const int* in_sizes, int n_in,
                              void* d_out, int out_size, void* d_ws, size_t ws_size,
                              hipStream_t stream) {
    const float* hs  = (const float*)d_in[0];
    const float* W   = (const float*)d_in[1];
    const float* fb  = (const float*)d_in[2];
    const float* bb  = (const float*)d_in[3];
    const int* sent  = (const int*)d_in[4];
    const int* bs    = (const int*)d_in[5];
    const int total  = in_sizes[4];
    const int T      = in_sizes[5];
    const int V      = in_sizes[2];
    const int D      = in_sizes[1] / V;
    const int D2     = in_sizes[0] / total;
    const int Mcap   = ((2 * total) + 127) & ~127;   // upper bound on packed rows

    char* p = (char*)d_ws;
    int*   hdr     = (int*)p;            p += 256;
    float* fhdr    = (float*)p;          p += 256;
    int*   row_ctx = (int*)p;            p += (size_t)Mcap * 4;
    int*   row_tok = (int*)p;            p += (size_t)Mcap * 4;
    float* S       = (float*)p;          p += (size_t)Mcap * 4;
    float* goldv   = (float*)p;          p += (size_t)Mcap * 4;
    __hip_bfloat16* Hc = (__hip_bfloat16*)p; p += (size_t)Mcap * D * 2;
    __hip_bfloat16* Wb = (__hip_bfloat16*)p;
    const size_t need_wb = (size_t)(p - (char*)d_ws) + (size_t)V * D * 2;

    prep_kernel<<<1, 256, 0, stream>>>(bs, T, sent, hdr, fhdr, row_ctx, row_tok);
    gather_kernel<<<Mcap, 256, 0, stream>>>(hs, row_ctx, hdr, Hc, S, D2, D);

    dim3 grid(V / 128, Mcap / 128);
    if (ws_size >= need_wb) {
        long n4 = (long)V * D / 4;
        wconv_kernel<<<(int)((n4 + 255) / 256), 256, 0, stream>>>(W, Wb, n4);
        gemm_lse_kernel<false><<<grid, 256, 0, stream>>>(Hc, (const void*)Wb, fb, bb, S, hdr, D);
    } else {
        gemm_lse_kernel<true><<<grid, 256, 0, stream>>>(Hc, (const void*)W, fb, bb, S, hdr, D);
    }

    gold_kernel<<<Mcap, 256, 0, stream>>>(hs, W, fb, bb, row_ctx, row_tok, hdr, goldv, D2, D);
    final_kernel<<<1, 256, 0, stream>>>(S, goldv, hdr, fhdr, (float*)d_out);
}